// Round 8
// baseline (155.267 us; speedup 1.0000x reference)
//
#include <hip/hip_runtime.h>
#include <hip/hip_fp16.h>

#define BLANKC 59

typedef _Float16 half8 __attribute__((ext_vector_type(8)));
typedef _Float16 half4 __attribute__((ext_vector_type(4)));

// LDS-only fence: waits LDS queue, leaves global prefetches (vmcnt) in flight.
#define LDS_FENCE() asm volatile("s_waitcnt lgkmcnt(0)" ::: "memory")

// lane l <- lane l-1 (fill into lane 0)
__device__ __forceinline__ float wave_shr1(float x, float fill) {
    int r = __builtin_amdgcn_update_dpp(__float_as_int(fill), __float_as_int(x),
                                        0x138 /* WAVE_SHR:1 */, 0xF, 0xF, false);
    return __int_as_float(r);
}
// lane l <- lane l+1 (fill into lane 63)
__device__ __forceinline__ float wave_shl1(float x, float fill) {
    int r = __builtin_amdgcn_update_dpp(__float_as_int(fill), __float_as_int(x),
                                        0x130 /* WAVE_SHL:1 */, 0xF, 0xF, false);
    return __int_as_float(r);
}

template <int CTRL>
__device__ __forceinline__ float dpp_fmax(float x) {
    int r = __builtin_amdgcn_update_dpp(__float_as_int(x), __float_as_int(x),
                                        CTRL, 0xF, 0xF, false);
    return fmaxf(x, __int_as_float(r));
}
template <int CTRL>
__device__ __forceinline__ float dpp_addf(float x) {
    int r = __builtin_amdgcn_update_dpp(__float_as_int(x), __float_as_int(x),
                                        CTRL, 0xF, 0xF, false);
    return x + __int_as_float(r);
}
__device__ __forceinline__ float wave_max_bcast(float x) {
    x = dpp_fmax<0x111>(x); x = dpp_fmax<0x112>(x);
    x = dpp_fmax<0x114>(x); x = dpp_fmax<0x118>(x);
    x = dpp_fmax<0x142>(x); x = dpp_fmax<0x143>(x);
    return __int_as_float(__builtin_amdgcn_readlane(__float_as_int(x), 63));
}
__device__ __forceinline__ float wave_sum_bcast(float x) {
    x = dpp_addf<0x111>(x); x = dpp_addf<0x112>(x);
    x = dpp_addf<0x114>(x); x = dpp_addf<0x118>(x);
    x = dpp_addf<0x142>(x); x = dpp_addf<0x143>(x);
    return __int_as_float(__builtin_amdgcn_readlane(__float_as_int(x), 63));
}

// ---------------- Self-contained fwd/bwd scanner waves ----------------------
// One block (128 threads = 2 waves) per batch element. Each wave both
// PRODUCES (load logits -> softmax -> gather 46 slots) and CONSUMES (scan)
// its own 8-t chunks: wave 0 forward t=0..191, wave 1 backward t=383..192.
// No inter-wave handoff, no flags, no big staging array; loads prefetched
// ~2 chunks ahead. Join at the midpoint in log2 domain (flush-proof).
#define SCRS 68   // scr row stride in halves
#define SDS  24   // Sd row stride in halves (48 B, 16B-aligned rows)

__global__ __launch_bounds__(128)
void ctc_fused(const int* __restrict__ labels, const float* __restrict__ logits,
               float* __restrict__ out, int T, int V, int L, float inv_b) {
    const int b    = blockIdx.x;
    const int tid  = threadIdx.x;
    const int lane = tid & 63;
    const int wid  = tid >> 6;                       // 0: fwd, 1: bwd

    __shared__ __align__(16) __half scr[2][8][SCRS]; // per-wave softmax bounce
    __shared__ __align__(16) __half Sd[2][46 * SDS]; // per-wave 8-t emission tile
    __shared__ float fa0[64], fa1[64];               // fwd result for the join
    __shared__ int   labs[2][64];
    __shared__ int   esF_s, wdone;

    labs[wid][lane] = (lane < L) ? labels[(long)b * L + lane] : BLANKC;
    if (tid == 0) wdone = 0;
    __syncthreads();                                 // the only block barrier

    const int* mylab = labs[wid];

    // softmax lane mapping: 8 lanes cooperate per t
    const int tq = lane >> 3;                        // t within chunk (0..7)
    const int q  = lane & 7;                         // column group
    const int c0 = q * 8;
    const bool full = (q < 7);                       // q=7 covers cols 56..59 only
    const float* src = logits + (long)b * T * V;

    // gather map: 46 slots x 8 t = 368 entries over 64 lanes
    int gl[6], gr[6], gv[6]; bool gok[6];
    #pragma unroll
    for (int k = 0; k < 6; ++k) {
        const int i = lane + (k << 6);
        gok[k] = (i < 368);
        gl[k] = i >> 3; gr[k] = i & 7;
        gv[k] = (gok[k] && gl[k] < 45) ? mylab[gl[k]] : BLANKC;
    }

    // scan lane config
    const int labL = (lane < L) ? mylab[lane] : BLANKC;
    const int labP = (lane >= 1 && lane < L) ? mylab[lane - 1] : BLANKC;
    const float skipf = ((lane >= 1) && (lane < L) && (labL != BLANKC) && (labL != labP))
                        ? 1.0f : 0.0f;
    const unsigned long long mk = __ballot((lane < L) && (labL != BLANKC));
    const int len = __popcll(mk);

    const int rl = (lane < 45) ? lane : 45;
    const __half* rowL = &Sd[wid][rl * SDS];
    const __half* rowB = &Sd[wid][45 * SDS];
    const half8 hz = {};

    auto ld = [&](int ch, float4& P0, float4& P1) {
        const float* p = src + (ch * 8 + tq) * 60 + c0;
        P0 = *(const float4*)p;
        if (full) P1 = *(const float4*)(p + 4);
    };
    auto smx_gather = [&](float e0, float e1, float e2, float e3,
                          float e4, float e5, float e6, float e7) {
        float s = ((e0 + e1) + (e2 + e3)) + ((e4 + e5) + (e6 + e7));
        s = dpp_addf<0xB1>(s);                       // xor1 within quads
        s = dpp_addf<0x4E>(s);                       // xor2 within quads
        s += __shfl_xor(s, 4, 64);                   // xor4 -> 8-lane sum
        const float inv = __builtin_amdgcn_rcpf(s);
        const half4 p0 = { (_Float16)(e0 * inv), (_Float16)(e1 * inv),
                           (_Float16)(e2 * inv), (_Float16)(e3 * inv) };
        const half4 p1 = { (_Float16)(e4 * inv), (_Float16)(e5 * inv),
                           (_Float16)(e6 * inv), (_Float16)(e7 * inv) };
        *(half4*)&scr[wid][tq][c0]     = p0;
        *(half4*)&scr[wid][tq][c0 + 4] = p1;
        LDS_FENCE();                                 // scr retired (wave-local)
        #pragma unroll
        for (int k = 0; k < 6; ++k)
            if (gok[k]) Sd[wid][gl[k] * SDS + gr[k]] = scr[wid][gr[k]][gv[k]];
        LDS_FENCE();                                 // Sd retired
    };

    if (wid == 0) {
        // ---- forward: alpha over t = 0..191 (chunks 0..23 ascending) ----
        float a0 = 0.f, a1 = 0.f;
        int esum = 80;
        auto step = [&](float eL, float eB) {
            const float p   = wave_shr1(a1, 0.0f);
            const float t1  = a0 + a1;
            const float na0 = (a0 + p) * eB;
            const float na1 = fmaf(skipf, p, t1) * eL;
            a0 = na0; a1 = na1;
        };
        auto renorm = [&]() {
            const float m = wave_max_bcast(fmaxf(a0, a1));
            const int e = (__float_as_int(m) >> 23) & 0xff;
            int sexp = 207 - e;                      // scale max to ~2^80
            if (sexp > 127) sexp = 127;
            const float sc = __int_as_float((sexp + 127) << 23);
            a0 *= sc; a1 *= sc;
            esum += sexp;
        };
        auto body = [&](int ch, int pre, float4& P0, float4& P1, bool first) {
            const float e0 = __expf(P0.x), e1 = __expf(P0.y),
                        e2 = __expf(P0.z), e3 = __expf(P0.w);
            float e4 = 0.f, e5 = 0.f, e6 = 0.f, e7 = 0.f;
            if (full) { e4 = __expf(P1.x); e5 = __expf(P1.y);
                        e6 = __expf(P1.z); e7 = __expf(P1.w); }
            if (pre >= 0) ld(pre, P0, P1);           // prefetch 2 chunks ahead
            smx_gather(e0, e1, e2, e3, e4, e5, e6, e7);
            half8 cL = *(const half8*)rowL;
            half8 cB = *(const half8*)rowB;
            if (lane >= 45) cL = hz;                 // phantom s1 rows
            if (lane >= 46) cB = hz;                 // phantom s0 rows
            if (first) {
                a0 = (lane == 0) ? (float)cB[0] * 0x1p80f : 0.f;
                a1 = (lane == 0) ? (float)cL[0] * 0x1p80f : 0.f;
                #pragma unroll
                for (int i = 1; i < 8; ++i) step((float)cL[i], (float)cB[i]);
            } else {
                #pragma unroll
                for (int i = 0; i < 8; ++i) step((float)cL[i], (float)cB[i]);
            }
            renorm();
        };
        float4 X0, X1{0.f,0.f,0.f,0.f}, Y0, Y1{0.f,0.f,0.f,0.f};
        ld(0, X0, X1); ld(1, Y0, Y1);
        for (int c = 0; c < 24; c += 2) {
            body(c,     (c + 2 < 24) ? c + 2 : -1, X0, X1, c == 0);
            body(c + 1, (c + 3 < 24) ? c + 3 : -1, Y0, Y1, false);
        }
        fa0[lane] = a0;                              // raw (2^esum scaled) alpha
        fa1[lane] = a1;
        if (lane == 0) esF_s = esum;
        LDS_FENCE();
        if (lane == 0)
            __hip_atomic_store(&wdone, 1, __ATOMIC_RELAXED,
                               __HIP_MEMORY_SCOPE_WORKGROUP);
        return;
    }

    // ---- backward: beta over t = 383..192 (chunks 47..24 descending) ----
    float g0 = (lane == len) ? 0x1p80f : 0.f;        // state 2*len (final blank)
    float g1 = (lane == len - 1) ? 0x1p80f : 0.f;    // state 2*len-1 (last label)
    int esum = 80;
    auto bstep = [&](float eL, float eB) {
        const float h0 = g0 * eB;
        const float h1 = g1 * eL;
        const float qq = wave_shl1(fmaf(skipf, h1, h0), 0.0f);  // from lane l+1
        g0 = h0 + h1;
        g1 = h1 + qq;
    };
    auto renormB = [&]() {
        const float m = wave_max_bcast(fmaxf(g0, g1));
        const int e = (__float_as_int(m) >> 23) & 0xff;
        int sexp = 207 - e;
        if (sexp > 127) sexp = 127;
        const float sc = __int_as_float((sexp + 127) << 23);
        g0 *= sc; g1 *= sc;
        esum += sexp;
    };
    auto bodyb = [&](int ch, int pre, float4& P0, float4& P1) {
        const float e0 = __expf(P0.x), e1 = __expf(P0.y),
                    e2 = __expf(P0.z), e3 = __expf(P0.w);
        float e4 = 0.f, e5 = 0.f, e6 = 0.f, e7 = 0.f;
        if (full) { e4 = __expf(P1.x); e5 = __expf(P1.y);
                    e6 = __expf(P1.z); e7 = __expf(P1.w); }
        if (pre >= 0) ld(pre, P0, P1);
        smx_gather(e0, e1, e2, e3, e4, e5, e6, e7);
        half8 cL = *(const half8*)rowL;
        half8 cB = *(const half8*)rowB;
        if (lane >= 45) cL = hz;
        if (lane >= 46) cB = hz;
        #pragma unroll
        for (int i = 7; i >= 0; --i) bstep((float)cL[i], (float)cB[i]);
        renormB();
    };
    float4 X0, X1{0.f,0.f,0.f,0.f}, Y0, Y1{0.f,0.f,0.f,0.f};
    ld(47, X0, X1); ld(46, Y0, Y1);
    for (int k = 0; k < 24; k += 2) {
        bodyb(47 - k,       (k + 2 < 24) ? 47 - (k + 2) : -1, X0, X1);
        bodyb(47 - (k + 1), (k + 3 < 24) ? 47 - (k + 3) : -1, Y0, Y1);
    }

    // ---- join (LOG2 domain, flush-proof): P = sum_s alpha_191[s]*beta_192[s]
    int d = __hip_atomic_load(&wdone, __ATOMIC_RELAXED, __HIP_MEMORY_SCOPE_WORKGROUP);
    while (!d) {
        __builtin_amdgcn_s_sleep(1);
        d = __hip_atomic_load(&wdone, __ATOMIC_RELAXED, __HIP_MEMORY_SCOPE_WORKGROUP);
    }
    asm volatile("" ::: "memory");
    const float t0 = __log2f(fa0[lane]) + __log2f(g0);   // -inf for dead states
    const float t1 = __log2f(fa1[lane]) + __log2f(g1);
    const float m  = wave_max_bcast(fmaxf(t0, t1));      // finite: some product > 0
    const float tt = wave_sum_bcast(exp2f(t0 - m) + exp2f(t1 - m));
    if (lane == 0) {
        const float log2P = m + __log2f(tt) - (float)(esum + esF_s);
        const float nll = -0.69314718055994531f * log2P;
        atomicAdd(out, nll * inv_b);
    }
}

extern "C" void kernel_launch(void* const* d_in, const int* in_sizes, int n_in,
                              void* d_out, int out_size, void* d_ws, size_t ws_size,
                              hipStream_t stream) {
    const int* labels   = (const int*)d_in[0];
    const float* logits = (const float*)d_in[1];
    float* out          = (float*)d_out;
    (void)d_ws; (void)ws_size;

    const int L = 45, V = 60;
    const int B = in_sizes[0] / L;
    const int T = in_sizes[1] / (B * V);

    hipMemsetAsync(out, 0, (size_t)out_size * sizeof(float), stream);
    ctc_fused<<<B, 128, 0, stream>>>(labels, logits, out, T, V, L, 1.0f / (float)B);
}

// Round 9
// 153.368 us; speedup vs baseline: 1.0124x; 1.0124x over previous
//
#include <hip/hip_runtime.h>
#include <hip/hip_fp16.h>

#define BLANKC 59

// LDS-only fence: waits LDS queue, leaves global prefetches (vmcnt) in flight.
#define LDS_FENCE() asm volatile("s_waitcnt lgkmcnt(0)" ::: "memory")

// lane l <- lane l-1 (fill into lane 0)
__device__ __forceinline__ float wave_shr1(float x, float fill) {
    int r = __builtin_amdgcn_update_dpp(__float_as_int(fill), __float_as_int(x),
                                        0x138 /* WAVE_SHR:1 */, 0xF, 0xF, false);
    return __int_as_float(r);
}
// lane l <- lane l+1 (fill into lane 63)
__device__ __forceinline__ float wave_shl1(float x, float fill) {
    int r = __builtin_amdgcn_update_dpp(__float_as_int(fill), __float_as_int(x),
                                        0x130 /* WAVE_SHL:1 */, 0xF, 0xF, false);
    return __int_as_float(r);
}

template <int CTRL>
__device__ __forceinline__ float dpp_fmax(float x) {
    int r = __builtin_amdgcn_update_dpp(__float_as_int(x), __float_as_int(x),
                                        CTRL, 0xF, 0xF, false);
    return fmaxf(x, __int_as_float(r));
}
template <int CTRL>
__device__ __forceinline__ float dpp_addf(float x) {
    int r = __builtin_amdgcn_update_dpp(__float_as_int(x), __float_as_int(x),
                                        CTRL, 0xF, 0xF, false);
    return x + __int_as_float(r);
}
__device__ __forceinline__ float wave_max_bcast(float x) {
    x = dpp_fmax<0x111>(x); x = dpp_fmax<0x112>(x);
    x = dpp_fmax<0x114>(x); x = dpp_fmax<0x118>(x);
    x = dpp_fmax<0x142>(x); x = dpp_fmax<0x143>(x);
    return __int_as_float(__builtin_amdgcn_readlane(__float_as_int(x), 63));
}
__device__ __forceinline__ float wave_sum_bcast(float x) {
    x = dpp_addf<0x111>(x); x = dpp_addf<0x112>(x);
    x = dpp_addf<0x114>(x); x = dpp_addf<0x118>(x);
    x = dpp_addf<0x142>(x); x = dpp_addf<0x143>(x);
    return __int_as_float(__builtin_amdgcn_readlane(__float_as_int(x), 63));
}

// ---------------- Deep-pipelined self-contained fwd/bwd scanner waves -------
// One block (2 waves) per batch element: wave 0 forward t=0..191, wave 1
// backward t=383..192, log2-domain join at the midpoint (R7/R8 proven).
// Changes vs R8: (1) SIX chunk loads in flight per wave (rides out
// HBM-latency-under-fill-writeback, the common ~50us floor of R3-R8);
// (2) fp32 scr with nibble-swapped row permutation row(v)=8*(v&7)+(v>>3):
// softmax writes are 2-way bank-aliased (free), emission reads are two
// aligned ds_read_b128; no fp16 pack, no second LDS stage, one fence/chunk;
// (3) branchless scan init via virtual pre-t0 state.
__global__ __launch_bounds__(128)
void ctc_fused(const int* __restrict__ labels, const float* __restrict__ logits,
               float* __restrict__ out, int T, int V, int L, float inv_b) {
    const int b    = blockIdx.x;
    const int tid  = threadIdx.x;
    const int lane = tid & 63;
    const int wid  = tid >> 6;                       // 0: fwd, 1: bwd

    __shared__ float scrF[2][64 * 12];               // 6 KB: perm-row emission scratch
    __shared__ float fa0[64], fa1[64];               // fwd result for the join
    __shared__ int   labs[2][64];
    __shared__ int   esF_s, wdone;

    labs[wid][lane] = (lane < L) ? labels[(long)b * L + lane] : BLANKC;
    if (tid == 0) wdone = 0;
    __syncthreads();                                 // the only block barrier

    const int* mylab = labs[wid];
    const int tq = lane >> 3;                        // t within chunk (0..7)
    const int q  = lane & 7;                         // column group
    const int c0 = q * 8;
    const bool full = (q < 7);                       // q=7 covers cols 56..59 only
    const float* src = logits + (long)b * T * V;

    // scan lane config
    const int labL = (lane < L) ? mylab[lane] : BLANKC;
    const int labP = (lane >= 1 && lane < L) ? mylab[lane - 1] : BLANKC;
    const float skipf = ((lane >= 1) && (lane < L) && (labL != BLANKC) && (labL != labP))
                        ? 1.0f : 0.0f;
    const unsigned long long mk = __ballot((lane < L) && (labL != BLANKC));
    const int len = __popcll(mk);
    const float mL = (lane <= 44) ? 1.f : 0.f;       // state 2l+1 exists iff l<=44
    const float mB = (lane <= 45) ? 1.f : 0.f;       // state 2l   exists iff l<=45

    // emission read rows (perm-swizzled); perm(59) = (3<<3)|7 = 31
    const int labv = (lane < 45) ? mylab[lane] : BLANKC;
    const int prow = ((labv & 7) << 3) | (labv >> 3);
    float* scw = &scrF[wid][0];
    const float* rL = &scrF[wid][prow * 12];
    const float* rB = &scrF[wid][31 * 12];

    auto ld = [&](int ch, float4& P0, float4& P1) {
        const float* p = src + (ch * 8 + tq) * 60 + c0;
        P0 = *(const float4*)p;
        if (full) P1 = *(const float4*)(p + 4);
    };

    // consume P0/P1 (chunk loaded 6 iterations ago), immediately re-issue the
    // slot's next load, then softmax -> scr -> per-lane emission rows.
    auto produce = [&](float4& P0, float4& P1, int prech,
                       float4& l0, float4& l1, float4& b0, float4& b1) {
        const float e0 = __expf(P0.x), e1 = __expf(P0.y),
                    e2 = __expf(P0.z), e3 = __expf(P0.w);
        float e4 = 0.f, e5 = 0.f, e6 = 0.f, e7 = 0.f;
        if (full) { e4 = __expf(P1.x); e5 = __expf(P1.y);
                    e6 = __expf(P1.z); e7 = __expf(P1.w); }
        if (prech >= 0) ld(prech, P0, P1);           // 6-deep pipeline refill
        float s = ((e0 + e1) + (e2 + e3)) + ((e4 + e5) + (e6 + e7));
        s = dpp_addf<0xB1>(s);                       // xor1 within quads
        s = dpp_addf<0x4E>(s);                       // xor2 within quads
        s += __shfl_xor(s, 4, 64);                   // xor4 -> 8-lane sum
        const float inv = __builtin_amdgcn_rcpf(s);
        // value v=8q+j -> physical row 8j+q (2-way bank-aliased across lanes)
        scw[( 0 + q) * 12 + tq] = e0 * inv;
        scw[( 8 + q) * 12 + tq] = e1 * inv;
        scw[(16 + q) * 12 + tq] = e2 * inv;
        scw[(24 + q) * 12 + tq] = e3 * inv;
        scw[(32 + q) * 12 + tq] = e4 * inv;          // q=7: junk rows 39/47/55/63,
        scw[(40 + q) * 12 + tq] = e5 * inv;          // never read (v=60..63)
        scw[(48 + q) * 12 + tq] = e6 * inv;
        scw[(56 + q) * 12 + tq] = e7 * inv;
        LDS_FENCE();                                 // wave-synchronous: all writes in
        l0 = *(const float4*)rL; l1 = *(const float4*)(rL + 4);
        b0 = *(const float4*)rB; b1 = *(const float4*)(rB + 4);
    };

    if (wid == 0) {
        // ---- forward: alpha over t = 0..191 (chunks 0..23 ascending) ----
        float a0 = (lane == 0) ? 0x1p80f : 0.f;      // virtual pre-t0 state
        float a1 = 0.f;                              // (first step reproduces init)
        int esum = 80;
        auto step = [&](float eL, float eB) {
            const float p   = wave_shr1(a1, 0.0f);
            const float t1  = a0 + a1;
            const float na0 = (a0 + p) * (eB * mB);
            const float na1 = fmaf(skipf, p, t1) * (eL * mL);
            a0 = na0; a1 = na1;
        };
        auto renorm = [&]() {
            const float m = wave_max_bcast(fmaxf(a0, a1));
            const int e = (__float_as_int(m) >> 23) & 0xff;
            int sexp = 207 - e;                      // scale max to ~2^80
            if (sexp > 127) sexp = 127;
            const float sc = __int_as_float((sexp + 127) << 23);
            a0 *= sc; a1 *= sc;
            esum += sexp;
        };
        float4 X0[6], X1[6];
        #pragma unroll
        for (int s = 0; s < 6; ++s) ld(s, X0[s], X1[s]);
        for (int g = 0; g < 24; g += 6) {
            #pragma unroll
            for (int s = 0; s < 6; ++s) {
                const int c = g + s;
                float4 l0, l1, b0, b1;
                produce(X0[s], X1[s], (c + 6 < 24) ? c + 6 : -1, l0, l1, b0, b1);
                step(l0.x, b0.x); step(l0.y, b0.y); step(l0.z, b0.z); step(l0.w, b0.w);
                step(l1.x, b1.x); step(l1.y, b1.y); step(l1.z, b1.z); step(l1.w, b1.w);
                renorm();
            }
        }
        fa0[lane] = a0;                              // raw (2^esum scaled) alpha
        fa1[lane] = a1;
        if (lane == 0) esF_s = esum;
        LDS_FENCE();
        if (lane == 0)
            __hip_atomic_store(&wdone, 1, __ATOMIC_RELAXED,
                               __HIP_MEMORY_SCOPE_WORKGROUP);
        return;
    }

    // ---- backward: beta over t = 383..192 (chunks 47..24 descending) ----
    float g0 = (lane == len) ? 0x1p80f : 0.f;        // state 2*len (final blank)
    float g1 = (lane == len - 1) ? 0x1p80f : 0.f;    // state 2*len-1 (last label)
    int esum = 80;
    auto bstep = [&](float eL, float eB) {
        const float h0 = g0 * (eB * mB);
        const float h1 = g1 * (eL * mL);
        const float qq = wave_shl1(fmaf(skipf, h1, h0), 0.0f);  // from lane l+1
        g0 = h0 + h1;
        g1 = h1 + qq;
    };
    auto renormB = [&]() {
        const float m = wave_max_bcast(fmaxf(g0, g1));
        const int e = (__float_as_int(m) >> 23) & 0xff;
        int sexp = 207 - e;
        if (sexp > 127) sexp = 127;
        const float sc = __int_as_float((sexp + 127) << 23);
        g0 *= sc; g1 *= sc;
        esum += sexp;
    };
    {
        float4 X0[6], X1[6];
        #pragma unroll
        for (int s = 0; s < 6; ++s) ld(47 - s, X0[s], X1[s]);
        for (int g = 0; g < 24; g += 6) {
            #pragma unroll
            for (int s = 0; s < 6; ++s) {
                const int i = g + s;                 // 0..23, chunk = 47-i
                float4 l0, l1, b0, b1;
                produce(X0[s], X1[s], (i + 6 < 24) ? 47 - (i + 6) : -1, l0, l1, b0, b1);
                bstep(l1.w, b1.w); bstep(l1.z, b1.z); bstep(l1.y, b1.y); bstep(l1.x, b1.x);
                bstep(l0.w, b0.w); bstep(l0.z, b0.z); bstep(l0.y, b0.y); bstep(l0.x, b0.x);
                renormB();
            }
        }
    }

    // ---- join (LOG2 domain, flush-proof): P = sum_s alpha_191[s]*beta_192[s]
    int d = __hip_atomic_load(&wdone, __ATOMIC_RELAXED, __HIP_MEMORY_SCOPE_WORKGROUP);
    while (!d) {
        __builtin_amdgcn_s_sleep(1);
        d = __hip_atomic_load(&wdone, __ATOMIC_RELAXED, __HIP_MEMORY_SCOPE_WORKGROUP);
    }
    asm volatile("" ::: "memory");
    const float t0 = __log2f(fa0[lane]) + __log2f(g0);   // -inf for dead states
    const float t1 = __log2f(fa1[lane]) + __log2f(g1);
    const float m  = wave_max_bcast(fmaxf(t0, t1));      // finite: some product > 0
    const float tt = wave_sum_bcast(exp2f(t0 - m) + exp2f(t1 - m));
    if (lane == 0) {
        const float log2P = m + __log2f(tt) - (float)(esum + esF_s);
        const float nll = -0.69314718055994531f * log2P;
        atomicAdd(out, nll * inv_b);
    }
}

extern "C" void kernel_launch(void* const* d_in, const int* in_sizes, int n_in,
                              void* d_out, int out_size, void* d_ws, size_t ws_size,
                              hipStream_t stream) {
    const int* labels   = (const int*)d_in[0];
    const float* logits = (const float*)d_in[1];
    float* out          = (float*)d_out;
    (void)d_ws; (void)ws_size;

    const int L = 45, V = 60;
    const int B = in_sizes[0] / L;
    const int T = in_sizes[1] / (B * V);

    hipMemsetAsync(out, 0, (size_t)out_size * sizeof(float), stream);
    ctc_fused<<<B, 128, 0, stream>>>(labels, logits, out, T, V, L, 1.0f / (float)B);
}